// Round 1
// baseline (307.005 us; speedup 1.0000x reference)
//
#include <hip/hip_runtime.h>
#include <hip/hip_bf16.h>

// Problem constants
#define N_NODES 4096
#define BATCH   128
#define DD      32           // D_IN == D_OUT

typedef float  f32x4  __attribute__((ext_vector_type(4)));
typedef __bf16 bf16x8 __attribute__((ext_vector_type(8)));
typedef int    i32x4  __attribute__((ext_vector_type(4)));
typedef int    i32x8  __attribute__((ext_vector_type(8)));

#define PREP_BLOCKS 2048
#define TR_BLOCKS   4096   // 64x64 tiles

// async global->LDS, 16 B per lane. LDS dest must be linear in lane (uniform base + lane*16).
__device__ __forceinline__ void async_copy16(const void* g, void* l) {
    __builtin_amdgcn_global_load_lds(
        (const __attribute__((address_space(1))) unsigned int*)g,
        (__attribute__((address_space(3))) unsigned int*)l,
        16, 0, 0);
}

// pack 4 floats -> 4 fp8 e4m3 bytes (OCP), one dword
__device__ __forceinline__ unsigned pack_fp8x4(float a, float b, float c, float d) {
    int v = __builtin_amdgcn_cvt_pk_fp8_f32(a, b, 0, false);   // bytes 0,1
    v     = __builtin_amdgcn_cvt_pk_fp8_f32(c, d, v, true);    // bytes 2,3
    return (unsigned)v;
}

// ---------------------------------------------------------------------------
// Fused pre-stage (UNCHANGED this round). Blocks [0, PREP_BLOCKS): per 16-row
// tile of x3 [524288 x 32]:
//   T8[m=(b*32+q)][i] = fp8( x @ Wn )   (A operand for the fp8 GEMM)
//   U[b][i][q]        = f32( x @ Ws )   (self part, pre-relu, into d_out)
// Blocks [PREP_BLOCKS, +TR_BLOCKS): adjT8[j][i] = fp8( adj[i][j] * 4096 )
//   (2^12 scale removed exactly by the GEMM's B e8m0 scale byte 0x73)
// ---------------------------------------------------------------------------
__global__ __launch_bounds__(256) void k_pre(
    const float* __restrict__ x, const float* __restrict__ adj,
    const float* __restrict__ Wn, const float* __restrict__ Ws,
    unsigned char* __restrict__ T8, unsigned char* __restrict__ adjT8,
    float* __restrict__ out)
{
    __shared__ float ts[64][65];
    const int tid = threadIdx.x;

    if (blockIdx.x < PREP_BLOCKS) {
        // ---- prep branch (MFMA, no LDS) ----
        const int lane = tid & 63;
        const int gw   = (blockIdx.x * 256 + tid) >> 6;  // wave id 0..8191
        const int m    = lane & 15;   // A row / C col index
        const int quad = lane >> 4;   // k-quad

        // B fragments: Bt[n][k] with n=lane&15, k=quad*8+j  ->  W[k*32+n]
        bf16x8 bn[2], bs[2];
#pragma unroll
        for (int h = 0; h < 2; ++h) {
            const int n = m + h * 16;
#pragma unroll
            for (int j = 0; j < 8; ++j) {
                const int k = quad * 8 + j;
                bn[h][j] = (__bf16)Wn[k * 32 + n];
                bs[h][j] = (__bf16)Ws[k * 32 + n];
            }
        }

        for (int t = gw; t < 32768; t += 8192) {       // 16-row tiles, 4 iters/wave
            const int row0 = t << 4;                   // global row = b*4096 + i0
            const int b    = row0 >> 12;
            const int i0   = row0 & 4095;

            const float4* xp = (const float4*)(x + (size_t)(row0 + m) * DD + quad * 8);
            const float4 x0 = xp[0], x1 = xp[1];
            bf16x8 a;
            a[0] = (__bf16)x0.x; a[1] = (__bf16)x0.y; a[2] = (__bf16)x0.z; a[3] = (__bf16)x0.w;
            a[4] = (__bf16)x1.x; a[5] = (__bf16)x1.y; a[6] = (__bf16)x1.z; a[7] = (__bf16)x1.w;

            const f32x4 z = {};
            const f32x4 cT0 = __builtin_amdgcn_mfma_f32_16x16x32_bf16(a, bn[0], z, 0, 0, 0);
            const f32x4 cT1 = __builtin_amdgcn_mfma_f32_16x16x32_bf16(a, bn[1], z, 0, 0, 0);
            const f32x4 cU0 = __builtin_amdgcn_mfma_f32_16x16x32_bf16(a, bs[0], z, 0, 0, 0);
            const f32x4 cU1 = __builtin_amdgcn_mfma_f32_16x16x32_bf16(a, bs[1], z, 0, 0, 0);

            // C/D: col=lane&15, row=quad*4+reg (i-local, 4 consecutive)
            *(unsigned*)&T8[((size_t)(b * 32 + m))      * N_NODES + i0 + quad * 4] =
                pack_fp8x4(cT0[0], cT0[1], cT0[2], cT0[3]);
            *(unsigned*)&T8[((size_t)(b * 32 + m + 16)) * N_NODES + i0 + quad * 4] =
                pack_fp8x4(cT1[0], cT1[1], cT1[2], cT1[3]);

            float* ub = out + (size_t)b * (N_NODES * DD) + (size_t)(i0 + quad * 4) * DD;
#pragma unroll
            for (int r = 0; r < 4; ++r) {   // full 64B sectors per instr
                ub[r * DD + m]      = cU0[r];
                ub[r * DD + m + 16] = cU1[r];
            }
        }
    } else {
        // ---- transpose branch ----
        const int bid = blockIdx.x - PREP_BLOCKS;
        const int cx  = tid & 63;
        const int cy  = tid >> 6;
        const int i0  = (bid >> 6) << 6;
        const int j0  = (bid & 63) << 6;
#pragma unroll
        for (int r = 0; r < 16; ++r) {
            const int row = cy * 16 + r;
            ts[row][cx] = adj[(size_t)(i0 + row) * N_NODES + j0 + cx];
        }
        __syncthreads();
        const int il = (tid & 7) * 8;
        const int jb = tid >> 3;          // 0..31
#pragma unroll
        for (int rr = 0; rr < 2; ++rr) {
            const int jl = jb + rr * 32;
            float v[8];
#pragma unroll
            for (int k = 0; k < 8; ++k) v[k] = ts[il + k][jl] * 4096.0f;
            uint2 p;
            p.x = pack_fp8x4(v[0], v[1], v[2], v[3]);
            p.y = pack_fp8x4(v[4], v[5], v[6], v[7]);
            *(uint2*)&adjT8[(size_t)(j0 + jl) * N_NODES + i0 + il] = p;
        }
    }
}

// ---------------------------------------------------------------------------
// GEMM v2: C[m][j] = sum_i T[m][i]*adjT[j][i] — 4096^3 MX-fp8.
//   Block tile 256(M) x 128(N), BK = 128 B, 4 waves (2M x 2N), wave tile
//   128x64 -> 8x4 fragments of 16x16x128 f8f6f4 (85 FLOP per LDS-read-byte
//   vs 64 before; LDS reads 2 GB -> 1.5 GB, LDS writes 1 GB -> 0.5 GB).
//   3-deep LDS ring (3 x 48 KB = 144 KB): iter t stages tile t+2 into the
//   buffer last read at iter t-1 (sealed by that iter's barrier -> race-free),
//   computes tile t, then waits vmcnt(12): clears tile t+1's 12 loads while
//   tile t+2's 12 stay in flight ACROSS the raw s_barrier (no vmcnt(0) drain
//   in the main loop -> removes the m97-style barrier-drain stall).
//   XOR swizzle unchanged: LDS chunk (r, c16) holds global chunk c16^(r&7);
//   read chunk (2lq+h)^(lr&7).
//           out[b*131072 + j*32 + q] = relu(U + C),  m = b*32+q
// ---------------------------------------------------------------------------
__global__ __launch_bounds__(256, 1) void k_gemm_neigh(
    const unsigned char* __restrict__ A8,   // T8    [4096][4096] fp8
    const unsigned char* __restrict__ B8,   // adjT8 [4096][4096] fp8 (x4096)
    float* __restrict__ out)                // holds U; RMW + relu
{
    __shared__ alignas(16) unsigned char As[3 * 256 * 128];   // 96 KB
    __shared__ alignas(16) unsigned char Bs[3 * 128 * 128];   // 48 KB

    const int tid   = threadIdx.x;
    const int lane  = tid & 63;
    const int wave  = tid >> 6;
    const int lr    = lane & 15;   // row (A) / col (B) within 16-tile
    const int lq    = lane >> 4;   // k-chunk (32 bytes)
    const int sw    = lr & 7;      // read-side XOR swizzle
    const int waveM = ((wave >> 1) & 1) * 128;
    const int waveN = (wave & 1) * 64;

    // bijective XCD swizzle: 512 wgs, 8 XCDs, 64 contiguous wgs per XCD
    const int wg = (blockIdx.x & 7) * 64 + (blockIdx.x >> 3);
    const int Mb = (wg >> 5) << 8;   // 16 m-blocks of 256
    const int Nb = (wg & 31) << 7;   // 32 n-blocks of 128

    // staging: row = n*32 + tid>>3, chunk (tid&7) pre-swizzled by row&7
    const int    srow = tid >> 3;
    const int    scol = ((tid & 7) ^ (srow & 7)) * 16;
    const size_t aoff = (size_t)(Mb + srow) * 4096 + scol;
    const size_t boff = (size_t)(Nb + srow) * 4096 + scol;
    char* const  lA   = (char*)As + tid * 16;
    char* const  lB   = (char*)Bs + tid * 16;

    f32x4 acc[8][4] = {};

#define STAGE(bufi, k0)                                                      \
    {                                                                        \
        _Pragma("unroll")                                                    \
        for (int n = 0; n < 8; ++n)                                          \
            async_copy16(A8 + aoff + (size_t)(n * 32) * 4096 + (k0),         \
                         lA + (bufi) * 32768 + n * 4096);                    \
        _Pragma("unroll")                                                    \
        for (int n = 0; n < 4; ++n)                                          \
            async_copy16(B8 + boff + (size_t)(n * 32) * 4096 + (k0),         \
                         lB + (bufi) * 16384 + n * 4096);                    \
    }

    // prologue: tiles 0 and 1 in flight; wait tile 0 (allow tile 1's 12)
    STAGE(0, 0);
    STAGE(1, 128);
    asm volatile("s_waitcnt vmcnt(12)" ::: "memory");
    __builtin_amdgcn_s_barrier();

    for (int t = 0; t < 32; ++t) {
        const int bc = t % 3;
        if (t + 2 < 32) {
            const int bs = (t + 2) % 3;
            STAGE(bs, (t + 2) * 128);     // issue first: max latency overlap
        }

        const unsigned char* const Ab = As + bc * 32768;
        const unsigned char* const Bb = Bs + bc * 16384;
        const int c0 = ((2 * lq)     ^ sw) * 16;
        const int c1 = ((2 * lq + 1) ^ sw) * 16;

        i32x8 bf[4];
#pragma unroll
        for (int fn = 0; fn < 4; ++fn) {
            const int rb = (waveN + fn * 16 + lr) * 128;
            const i32x4 blo = *(const i32x4*)&Bb[rb + c0];
            const i32x4 bhi = *(const i32x4*)&Bb[rb + c1];
            bf[fn][0]=blo[0]; bf[fn][1]=blo[1]; bf[fn][2]=blo[2]; bf[fn][3]=blo[3];
            bf[fn][4]=bhi[0]; bf[fn][5]=bhi[1]; bf[fn][6]=bhi[2]; bf[fn][7]=bhi[3];
        }
#pragma unroll
        for (int fm = 0; fm < 8; ++fm) {
            const int ra = (waveM + fm * 16 + lr) * 128;
            const i32x4 alo = *(const i32x4*)&Ab[ra + c0];
            const i32x4 ahi = *(const i32x4*)&Ab[ra + c1];
            i32x8 af;
            af[0]=alo[0]; af[1]=alo[1]; af[2]=alo[2]; af[3]=alo[3];
            af[4]=ahi[0]; af[5]=ahi[1]; af[6]=ahi[2]; af[7]=ahi[3];
#pragma unroll
            for (int fn = 0; fn < 4; ++fn)
                acc[fm][fn] = __builtin_amdgcn_mfma_scale_f32_16x16x128_f8f6f4(
                    af, bf[fn], acc[fm][fn],
                    0, 0,              // fp8(e4m3) x fp8(e4m3)
                    0, 0x7F,           // A scale: 2^0
                    0, 0x73);          // B scale: 2^-12 (undo adj*4096)
        }

        // tile t fully consumed by the MFMAs above (lgkm waits precede them).
        // Clear tile t+1's loads, keep tile t+2's 12 in flight across barrier.
        if (t + 1 < 32) {
            if (t + 2 < 32) { asm volatile("s_waitcnt vmcnt(12)" ::: "memory"); }
            else            { asm volatile("s_waitcnt vmcnt(0)"  ::: "memory"); }
            __builtin_amdgcn_s_barrier();
        }
    }
#undef STAGE

    // epilogue: C/D col=lane&15 (=j), row=quad*4+reg (=m); q=m&31 contiguous
#pragma unroll
    for (int fm = 0; fm < 8; ++fm) {
        const int gm0 = Mb + waveM + fm * 16 + lq * 4;
        const int b   = gm0 >> 5;
        const int q0  = gm0 & 31;
#pragma unroll
        for (int fn = 0; fn < 4; ++fn) {
            const int gj = Nb + waveN + fn * 16 + lr;
            float* p = out + (size_t)b * (N_NODES * DD) + (size_t)gj * DD + q0;
            const float4 u = *(const float4*)p;
            float4 v;
            v.x = fmaxf(acc[fm][fn][0] + u.x, 0.0f);
            v.y = fmaxf(acc[fm][fn][1] + u.y, 0.0f);
            v.z = fmaxf(acc[fm][fn][2] + u.z, 0.0f);
            v.w = fmaxf(acc[fm][fn][3] + u.w, 0.0f);
            *(float4*)p = v;
        }
    }
}

extern "C" void kernel_launch(void* const* d_in, const int* in_sizes, int n_in,
                              void* d_out, int out_size, void* d_ws, size_t ws_size,
                              hipStream_t stream) {
    const float* x   = (const float*)d_in[0];  // [128, 4096*32]
    const float* adj = (const float*)d_in[1];  // [4096, 4096]
    const float* Wn  = (const float*)d_in[2];  // [32, 32]
    const float* Ws  = (const float*)d_in[3];  // [32, 32]
    float* out = (float*)d_out;                // [128, 4096*32]

    // workspace: T8 fp8 (16 MB) | adjT8 fp8 (16 MB)
    unsigned char* T8    = (unsigned char*)d_ws;
    unsigned char* adjT8 = T8 + (size_t)N_NODES * N_NODES;

    hipLaunchKernelGGL(k_pre, dim3(PREP_BLOCKS + TR_BLOCKS), dim3(256), 0, stream,
                       x, adj, Wn, Ws, T8, adjT8, out);
    hipLaunchKernelGGL(k_gemm_neigh, dim3(512), dim3(256), 0, stream, T8, adjT8, out);
}

// Round 2
// 263.482 us; speedup vs baseline: 1.1652x; 1.1652x over previous
//
#include <hip/hip_runtime.h>
#include <hip/hip_bf16.h>

// Problem constants
#define N_NODES 4096
#define BATCH   128
#define DD      32           // D_IN == D_OUT

typedef float  f32x4  __attribute__((ext_vector_type(4)));
typedef __bf16 bf16x8 __attribute__((ext_vector_type(8)));
typedef int    i32x4  __attribute__((ext_vector_type(4)));
typedef int    i32x8  __attribute__((ext_vector_type(8)));

#define PREP_BLOCKS 2048
#define TR_BLOCKS   4096   // 64x64 tiles

// async global->LDS, 16 B per lane. LDS dest must be linear in lane (uniform base + lane*16).
__device__ __forceinline__ void async_copy16(const void* g, void* l) {
    __builtin_amdgcn_global_load_lds(
        (const __attribute__((address_space(1))) unsigned int*)g,
        (__attribute__((address_space(3))) unsigned int*)l,
        16, 0, 0);
}

// pack 4 floats -> 4 fp8 e4m3 bytes (OCP), one dword
__device__ __forceinline__ unsigned pack_fp8x4(float a, float b, float c, float d) {
    int v = __builtin_amdgcn_cvt_pk_fp8_f32(a, b, 0, false);   // bytes 0,1
    v     = __builtin_amdgcn_cvt_pk_fp8_f32(c, d, v, true);    // bytes 2,3
    return (unsigned)v;
}

// ---------------------------------------------------------------------------
// Pre-stage v3: self-part (U) computation REMOVED — it now lives in the GEMM
// epilogue (reads x directly, bit-identical math). This deletes 64 MB of U
// writes here + 64 MB of U reads in the gemm.
// Blocks [0, PREP_BLOCKS): per 16-row tile of x3 [524288 x 32]:
//   T8[m=(b*32+q)][i] = fp8( x @ Wn )   (A operand for the fp8 GEMM)
// Blocks [PREP_BLOCKS, +TR_BLOCKS): adjT8[j][i] = fp8( adj[i][j] * 4096 )
//   (2^12 scale removed exactly by the GEMM's B e8m0 scale byte 0x73)
// ---------------------------------------------------------------------------
__global__ __launch_bounds__(256) void k_pre(
    const float* __restrict__ x, const float* __restrict__ adj,
    const float* __restrict__ Wn,
    unsigned char* __restrict__ T8, unsigned char* __restrict__ adjT8)
{
    __shared__ float ts[64][65];
    const int tid = threadIdx.x;

    if (blockIdx.x < PREP_BLOCKS) {
        // ---- prep branch (MFMA, no LDS) ----
        const int lane = tid & 63;
        const int gw   = (blockIdx.x * 256 + tid) >> 6;  // wave id 0..8191
        const int m    = lane & 15;   // A row / C col index
        const int quad = lane >> 4;   // k-quad

        // B fragments: Bt[n][k] with n=lane&15, k=quad*8+j  ->  W[k*32+n]
        bf16x8 bn[2];
#pragma unroll
        for (int h = 0; h < 2; ++h) {
            const int n = m + h * 16;
#pragma unroll
            for (int j = 0; j < 8; ++j) {
                const int k = quad * 8 + j;
                bn[h][j] = (__bf16)Wn[k * 32 + n];
            }
        }

        for (int t = gw; t < 32768; t += 8192) {       // 16-row tiles, 4 iters/wave
            const int row0 = t << 4;                   // global row = b*4096 + i0
            const int b    = row0 >> 12;
            const int i0   = row0 & 4095;

            const float4* xp = (const float4*)(x + (size_t)(row0 + m) * DD + quad * 8);
            const float4 x0 = xp[0], x1 = xp[1];
            bf16x8 a;
            a[0] = (__bf16)x0.x; a[1] = (__bf16)x0.y; a[2] = (__bf16)x0.z; a[3] = (__bf16)x0.w;
            a[4] = (__bf16)x1.x; a[5] = (__bf16)x1.y; a[6] = (__bf16)x1.z; a[7] = (__bf16)x1.w;

            const f32x4 z = {};
            const f32x4 cT0 = __builtin_amdgcn_mfma_f32_16x16x32_bf16(a, bn[0], z, 0, 0, 0);
            const f32x4 cT1 = __builtin_amdgcn_mfma_f32_16x16x32_bf16(a, bn[1], z, 0, 0, 0);

            // C/D: col=lane&15, row=quad*4+reg (i-local, 4 consecutive)
            *(unsigned*)&T8[((size_t)(b * 32 + m))      * N_NODES + i0 + quad * 4] =
                pack_fp8x4(cT0[0], cT0[1], cT0[2], cT0[3]);
            *(unsigned*)&T8[((size_t)(b * 32 + m + 16)) * N_NODES + i0 + quad * 4] =
                pack_fp8x4(cT1[0], cT1[1], cT1[2], cT1[3]);
        }
    } else {
        // ---- transpose branch ----
        const int bid = blockIdx.x - PREP_BLOCKS;
        const int cx  = tid & 63;
        const int cy  = tid >> 6;
        const int i0  = (bid >> 6) << 6;
        const int j0  = (bid & 63) << 6;
#pragma unroll
        for (int r = 0; r < 16; ++r) {
            const int row = cy * 16 + r;
            ts[row][cx] = adj[(size_t)(i0 + row) * N_NODES + j0 + cx];
        }
        __syncthreads();
        const int il = (tid & 7) * 8;
        const int jb = tid >> 3;          // 0..31
#pragma unroll
        for (int rr = 0; rr < 2; ++rr) {
            const int jl = jb + rr * 32;
            float v[8];
#pragma unroll
            for (int k = 0; k < 8; ++k) v[k] = ts[il + k][jl] * 4096.0f;
            uint2 p;
            p.x = pack_fp8x4(v[0], v[1], v[2], v[3]);
            p.y = pack_fp8x4(v[4], v[5], v[6], v[7]);
            *(uint2*)&adjT8[(size_t)(j0 + jl) * N_NODES + i0 + il] = p;
        }
    }
}

// ---------------------------------------------------------------------------
// GEMM (v1 structure, proven 98 us): C[m][j] = sum_i T[m][i]*adjT[j][i] —
// 4096^3 MX-fp8, 128x128 tile, BK=128B, 4 waves x (4x4) 16x16x128 f8f6f4,
// global_load_lds width 16, XOR-swizzled LDS (staging pre-swizzle + read
// swizzle). ~4 blocks/CU co-resident supply the latency hiding (the v2
// deep-pipeline experiment at 1 wave/SIMD regressed — do not repeat).
//
// NEW epilogue: self part U computed here from x, bit-identical to the old
// k_pre path: U[q][j] = mfma_bf16(Ws^T-frag, x-frag). Operand order chosen so
// D layout (row=q, col=j) matches the fp8 acc layout lane-for-lane — the add
// is pure per-lane register math. out becomes a pure store (no RMW read).
//           out[b*131072 + j*32 + q] = relu(U + C),  m = b*32+q
// ---------------------------------------------------------------------------
__global__ __launch_bounds__(256) void k_gemm_neigh(
    const unsigned char* __restrict__ A8,   // T8    [4096][4096] fp8
    const unsigned char* __restrict__ B8,   // adjT8 [4096][4096] fp8 (x4096)
    const float* __restrict__ x,            // [128][4096][32] f32
    const float* __restrict__ Ws,           // [32][32] f32
    float* __restrict__ out)                // [128][4096][32] pure store
{
    __shared__ alignas(16) unsigned char As[128 * 128];
    __shared__ alignas(16) unsigned char Bs[128 * 128];

    const int tid   = threadIdx.x;
    const int lane  = tid & 63;
    const int wave  = tid >> 6;
    const int bm    = blockIdx.y << 7;
    const int bn    = blockIdx.x << 7;
    const int waveM = (wave >> 1) << 6;
    const int waveN = (wave & 1) << 6;
    const int lr    = lane & 15;   // row (A) / col (B) within 16-tile
    const int lq    = lane >> 4;   // k-chunk (32 bytes)
    const int sw    = lr & 7;      // read-side XOR swizzle

    f32x4 acc[4][4] = {};

    // staging: row r = tid>>3 (+n*32); source chunk swizzled by r&7 so the
    // LDS image at (r, c16) holds global chunk c16 ^ (r&7)
    const int srow = tid >> 3;
    const int scol = ((tid & 7) ^ (srow & 7)) * 16;
    const unsigned char* ga = A8 + (size_t)(bm + srow) * 4096 + scol;
    const unsigned char* gb = B8 + (size_t)(bn + srow) * 4096 + scol;
    char* la = (char*)As + tid * 16;
    char* lb = (char*)Bs + tid * 16;

    for (int k0 = 0; k0 < 4096; k0 += 128) {
#pragma unroll
        for (int n = 0; n < 4; ++n) {
            async_copy16(ga + (size_t)(n * 32) * 4096 + k0, la + n * 4096);
            async_copy16(gb + (size_t)(n * 32) * 4096 + k0, lb + n * 4096);
        }
        __syncthreads();   // drains vmcnt -> LDS tiles complete

        i32x8 af[4], bfr[4];
#pragma unroll
        for (int t = 0; t < 4; ++t) {
            const int ra = (waveM + t * 16 + lr) * 128;
            const int rb = (waveN + t * 16 + lr) * 128;
            const int c0 = ((2 * lq)     ^ sw) * 16;
            const int c1 = ((2 * lq + 1) ^ sw) * 16;
            const i32x4 alo = *(const i32x4*)&As[ra + c0];
            const i32x4 ahi = *(const i32x4*)&As[ra + c1];
            const i32x4 blo = *(const i32x4*)&Bs[rb + c0];
            const i32x4 bhi = *(const i32x4*)&Bs[rb + c1];
            af[t][0]=alo[0]; af[t][1]=alo[1]; af[t][2]=alo[2]; af[t][3]=alo[3];
            af[t][4]=ahi[0]; af[t][5]=ahi[1]; af[t][6]=ahi[2]; af[t][7]=ahi[3];
            bfr[t][0]=blo[0]; bfr[t][1]=blo[1]; bfr[t][2]=blo[2]; bfr[t][3]=blo[3];
            bfr[t][4]=bhi[0]; bfr[t][5]=bhi[1]; bfr[t][6]=bhi[2]; bfr[t][7]=bhi[3];
        }
#pragma unroll
        for (int tm = 0; tm < 4; ++tm)
#pragma unroll
            for (int tn = 0; tn < 4; ++tn)
                acc[tm][tn] = __builtin_amdgcn_mfma_scale_f32_16x16x128_f8f6f4(
                    af[tm], bfr[tn], acc[tm][tn],
                    0, 0,              // cbsz=fp8(e4m3), blgp=fp8(e4m3)
                    0, 0x7F,           // A scale: 2^0
                    0, 0x73);          // B scale: 2^-12 (undo adj*4096)
        __syncthreads();
    }

    // ---- epilogue: U = bf16(x) @ bf16(Ws), computed in the SAME fragment
    // layout as acc (row=q=lq*4+reg, col=j=lr), then relu(acc+U) pure store.
    const f32x4 z = {};

    // Ws^T A-fragments: A[m=q][k=p] = Ws[p*32+q], q = lr + h*16, p = lq*8+j
    bf16x8 ws[2];
#pragma unroll
    for (int h = 0; h < 2; ++h)
#pragma unroll
        for (int j = 0; j < 8; ++j)
            ws[h][j] = (__bf16)Ws[(lq * 8 + j) * 32 + lr + h * 16];

    const int b0 = (bm + waveM) >> 5;    // wave's m-range = 64 rows = 2 batches
#pragma unroll
    for (int bb = 0; bb < 2; ++bb) {
        const int b = b0 + bb;
        // x B-fragments for this batch: B[n=j][k=p], n = lr, one per tn
        bf16x8 xa[4];
#pragma unroll
        for (int tn = 0; tn < 4; ++tn) {
            const int gj = bn + waveN + tn * 16 + lr;
            const float4* xp = (const float4*)(x + ((size_t)b * N_NODES + gj) * DD + lq * 8);
            const float4 x0 = xp[0], x1 = xp[1];
            xa[tn][0] = (__bf16)x0.x; xa[tn][1] = (__bf16)x0.y;
            xa[tn][2] = (__bf16)x0.z; xa[tn][3] = (__bf16)x0.w;
            xa[tn][4] = (__bf16)x1.x; xa[tn][5] = (__bf16)x1.y;
            xa[tn][6] = (__bf16)x1.z; xa[tn][7] = (__bf16)x1.w;
        }
#pragma unroll
        for (int hh = 0; hh < 2; ++hh) {
            const int tm = bb * 2 + hh;          // acc tile for (b, q-half hh)
            const int q0 = hh * 16 + lq * 4;     // q of acc reg 0
#pragma unroll
            for (int tn = 0; tn < 4; ++tn) {
                const f32x4 u = __builtin_amdgcn_mfma_f32_16x16x32_bf16(
                    ws[hh], xa[tn], z, 0, 0, 0);
                const int gj = bn + waveN + tn * 16 + lr;
                float* p = out + (size_t)b * (N_NODES * DD) + (size_t)gj * DD + q0;
                float4 v;
                v.x = fmaxf(acc[tm][tn][0] + u[0], 0.0f);
                v.y = fmaxf(acc[tm][tn][1] + u[1], 0.0f);
                v.z = fmaxf(acc[tm][tn][2] + u[2], 0.0f);
                v.w = fmaxf(acc[tm][tn][3] + u[3], 0.0f);
                *(float4*)p = v;
            }
        }
    }
}

extern "C" void kernel_launch(void* const* d_in, const int* in_sizes, int n_in,
                              void* d_out, int out_size, void* d_ws, size_t ws_size,
                              hipStream_t stream) {
    const float* x   = (const float*)d_in[0];  // [128, 4096*32]
    const float* adj = (const float*)d_in[1];  // [4096, 4096]
    const float* Wn  = (const float*)d_in[2];  // [32, 32]
    const float* Ws  = (const float*)d_in[3];  // [32, 32]
    float* out = (float*)d_out;                // [128, 4096*32]

    // workspace: T8 fp8 (16 MB) | adjT8 fp8 (16 MB)
    unsigned char* T8    = (unsigned char*)d_ws;
    unsigned char* adjT8 = T8 + (size_t)N_NODES * N_NODES;

    hipLaunchKernelGGL(k_pre, dim3(PREP_BLOCKS + TR_BLOCKS), dim3(256), 0, stream,
                       x, adj, Wn, T8, adjT8);
    hipLaunchKernelGGL(k_gemm_neigh, dim3(32, 32), dim3(256), 0, stream,
                       T8, adjT8, x, Ws, out);
}